// Round 4
// baseline (404.964 us; speedup 1.0000x reference)
//
#include <hip/hip_runtime.h>
#include <stdint.h>

#define D_DIM 2048
#define K_DIM 64
#define T_DIM 2048
#define BT_DIM 16384   // B*T = 8*2048

typedef __attribute__((address_space(3))) uint32_t lds_u32;
typedef const __attribute__((address_space(1))) uint32_t glob_u32;

// ---------------------------------------------------------------------------
// prep1: softmax over k of w[d,:] -> pT[k,d] (transposed), plus per-block
// column min/max partials (block covers 4 d-rows; one wave per row, lane=k).
// ---------------------------------------------------------------------------
__global__ __launch_bounds__(256) void prep1_k(const float* __restrict__ w,
                                               float* __restrict__ pT,
                                               float* __restrict__ pmn,
                                               float* __restrict__ pmx) {
    const int lane = threadIdx.x & 63;
    const int wave = threadIdx.x >> 6;
    const int d = blockIdx.x * 4 + wave;
    const float v = w[d * K_DIM + lane];
    float m = v;
#pragma unroll
    for (int off = 32; off > 0; off >>= 1) m = fmaxf(m, __shfl_xor(m, off, 64));
    const float e = expf(v - m);
    float s = e;
#pragma unroll
    for (int off = 32; off > 0; off >>= 1) s += __shfl_xor(s, off, 64);
    pT[(size_t)lane * D_DIM + d] = e / s;

    __shared__ float col[4][64];
    col[wave][lane] = v;
    __syncthreads();
    if (wave == 0) {
        const float a = col[0][lane], b = col[1][lane];
        const float c = col[2][lane], dd = col[3][lane];
        pmn[blockIdx.x * 64 + lane] = fminf(fminf(a, b), fminf(c, dd));
        pmx[blockIdx.x * 64 + lane] = fmaxf(fmaxf(a, b), fmaxf(c, dd));
    }
}

// ---------------------------------------------------------------------------
// prep2: reduce 512 partials per column -> mn[k], inv[k]. One wave per k.
// ---------------------------------------------------------------------------
__global__ __launch_bounds__(256) void prep2_k(const float* __restrict__ pmn,
                                               const float* __restrict__ pmx,
                                               float* __restrict__ mn,
                                               float* __restrict__ inv) {
    const int lane = threadIdx.x & 63;
    const int wave = threadIdx.x >> 6;
    const int k = blockIdx.x * 4 + wave;
    float a = 1e30f, b = -1e30f;
#pragma unroll
    for (int i = 0; i < 8; ++i) {
        const int blk = lane + 64 * i;
        a = fminf(a, pmn[blk * 64 + k]);
        b = fmaxf(b, pmx[blk * 64 + k]);
    }
#pragma unroll
    for (int off = 32; off > 0; off >>= 1) {
        a = fminf(a, __shfl_xor(a, off, 64));
        b = fmaxf(b, __shfl_xor(b, off, 64));
    }
    if (lane == 0) { mn[k] = a; inv[k] = 1.0f / (b - a); }
}

// ---------------------------------------------------------------------------
// prep3: nT[k,d] = (w[d,k]-mn[k])*inv[k]. Coalesced writes, wide grid.
// ---------------------------------------------------------------------------
__global__ __launch_bounds__(256) void prep3_k(const float* __restrict__ w,
                                               const float* __restrict__ mn,
                                               const float* __restrict__ inv,
                                               float* __restrict__ nT) {
    const int k = blockIdx.x >> 3;
    const int d = (blockIdx.x & 7) * 256 + threadIdx.x;
    nT[(size_t)k * D_DIM + d] = (w[d * K_DIM + k] - mn[k]) * inv[k];
}

// ---------------------------------------------------------------------------
// gemm_stats: scores = X @ P -> per-row (argmax, sign).
// Block = 32 rows; 4 waves split D (512 each); lane = k.
// x double-buffered through LDS via global_load_lds (vmcnt(8) never-drain
// prefetch); p fragments per-lane in VGPRs (16 float4 per 64-d chunk,
// amortized over 32 rows). Cross-wave reduce + 64-lane argmax at the end.
// ---------------------------------------------------------------------------
__global__ __launch_bounds__(256) void gemm_stats_k(const float* __restrict__ x,
                                                    const float* __restrict__ pT,
                                                    int* __restrict__ stats) {
    const int lane = threadIdx.x & 63;
    const int wave = threadIdx.x >> 6;
    const int r0 = blockIdx.x * 32;
    const int dw0 = wave * (D_DIM / 4);

    __shared__ float smem[16384];          // 64 KB: 4 waves x 2 bufs x 2048 floats
    float* xs = smem + wave * 4096;

    float acc[32];
#pragma unroll
    for (int r = 0; r < 32; ++r) acc[r] = 0.0f;

    const float* xg = x + (size_t)r0 * D_DIM + dw0;
    const float* pg = pT + (size_t)lane * D_DIM + dw0;
    const int srow = lane >> 4;            // 0..3
    const int scol = (lane & 15) * 4;      // 0..60

    // prologue: stage chunk 0 into buf 0 (8 x 1KB coalesced DMA)
#pragma unroll
    for (int j = 0; j < 8; ++j) {
        const float* src = xg + (size_t)(j * 4 + srow) * D_DIM + scol;
        __builtin_amdgcn_global_load_lds((glob_u32*)src, (lds_u32*)(xs + j * 256),
                                         16, 0, 0);
    }

    for (int c = 0; c < 8; ++c) {
        // p fragment for this chunk (per-lane; L2-resident)
        const float* pc = pg + c * 64;
        float4 pv[16];
#pragma unroll
        for (int j = 0; j < 16; ++j) pv[j] = *(const float4*)(pc + j * 4);

        // prefetch next chunk into the other buffer (c==7 re-stages chunk 0:
        // harmless dummy that keeps the vmcnt(8) pattern uniform)
        const int nc = (c + 1) & 7;
        float* xn = xs + ((c + 1) & 1) * 2048;
#pragma unroll
        for (int j = 0; j < 8; ++j) {
            const float* src = xg + (size_t)(j * 4 + srow) * D_DIM + nc * 64 + scol;
            __builtin_amdgcn_global_load_lds((glob_u32*)src,
                                             (lds_u32*)(xn + j * 256), 16, 0, 0);
        }
        // drain everything except the 8 prefetch loads just issued
        asm volatile("s_waitcnt vmcnt(8)" ::: "memory");

        const float* xb = xs + (c & 1) * 2048;
#pragma unroll
        for (int r = 0; r < 32; ++r) {
            float a = acc[r];
#pragma unroll
            for (int j = 0; j < 16; ++j) {
                const float4 xv = *(const float4*)(xb + r * 64 + j * 4);  // broadcast
                a = fmaf(xv.x, pv[j].x, a);
                a = fmaf(xv.y, pv[j].y, a);
                a = fmaf(xv.z, pv[j].z, a);
                a = fmaf(xv.w, pv[j].w, a);
            }
            acc[r] = a;
        }
    }

    __syncthreads();                        // all waves done with xs; alias as red
    float (*red)[32][64] = (float (*)[32][64])smem;   // 32 KB of the 64
#pragma unroll
    for (int r = 0; r < 32; ++r) red[wave][r][lane] = acc[r];
    __syncthreads();

#pragma unroll
    for (int rr = 0; rr < 8; ++rr) {
        const int r = wave * 8 + rr;
        float v = red[0][r][lane] + red[1][r][lane] + red[2][r][lane] + red[3][r][lane];
        int idx = lane;
#pragma unroll
        for (int off = 32; off > 0; off >>= 1) {
            const float ov = __shfl_xor(v, off, 64);
            const int oi = __shfl_xor(idx, off, 64);
            if (ov > v || (ov == v && oi < idx)) { v = ov; idx = oi; }
        }
        if (lane == 0) stats[r0 + r] = idx | ((v < 0.0f) ? (1 << 8) : 0);
    }
}

// ---------------------------------------------------------------------------
// output: out[r,d] = x[r,d]*(1+W), W from stats[r-1]; t==0 rows pass through.
// 4 rows per block.
// ---------------------------------------------------------------------------
__global__ __launch_bounds__(256) void output_k(const float* __restrict__ x,
                                                const float* __restrict__ nT,
                                                const int* __restrict__ stats,
                                                float* __restrict__ out) {
    const int base = blockIdx.x * 4;
#pragma unroll
    for (int rr = 0; rr < 4; ++rr) {
        const int row = base + rr;
        const int t = row & (T_DIM - 1);
        const float4* x4 = (const float4*)(x + (size_t)row * D_DIM);
        float4* o4 = (float4*)(out + (size_t)row * D_DIM);
        if (t == 0) {
#pragma unroll
            for (int it = 0; it < 2; ++it) {
                const int i = threadIdx.x + it * 256;
                o4[i] = x4[i];
            }
            continue;
        }
        const int s = stats[row - 1];
        const int ind = s & 0xff;
        const bool neg = (s >> 8) & 1;
        const float4* n4 = (const float4*)(nT + (size_t)ind * D_DIM);
#pragma unroll
        for (int it = 0; it < 2; ++it) {
            const int i = threadIdx.x + it * 256;
            const float4 xv = x4[i];
            const float4 nv = n4[i];
            float4 r;
            const float w0 = neg ? 1.0f - nv.x : nv.x;
            const float w1 = neg ? 1.0f - nv.y : nv.y;
            const float w2 = neg ? 1.0f - nv.z : nv.z;
            const float w3 = neg ? 1.0f - nv.w : nv.w;
            r.x = fmaf(xv.x, w0, xv.x);
            r.y = fmaf(xv.y, w1, xv.y);
            r.z = fmaf(xv.z, w2, xv.z);
            r.w = fmaf(xv.w, w3, xv.w);
            o4[i] = r;
        }
    }
}

extern "C" void kernel_launch(void* const* d_in, const int* in_sizes, int n_in,
                              void* d_out, int out_size, void* d_ws, size_t ws_size,
                              hipStream_t stream) {
    const float* x = (const float*)d_in[0];   // [B,T,D] fp32
    const float* w = (const float*)d_in[1];   // [D,K] fp32
    float* out = (float*)d_out;

    float* pT  = (float*)d_ws;                          // [K,D]   512 KB
    float* nT  = pT + (size_t)K_DIM * D_DIM;            // [K,D]   512 KB
    int* stats = (int*)(nT + (size_t)K_DIM * D_DIM);    // [B*T]    64 KB
    float* pmn = (float*)(stats + BT_DIM);              // [512,64] 128 KB
    float* pmx = pmn + 512 * 64;                        // [512,64] 128 KB
    float* mn  = pmx + 512 * 64;                        // [64]
    float* inv = mn + 64;                               // [64]

    prep1_k<<<D_DIM / 4, 256, 0, stream>>>(w, pT, pmn, pmx);
    prep2_k<<<K_DIM / 4, 256, 0, stream>>>(pmn, pmx, mn, inv);
    prep3_k<<<K_DIM * 8, 256, 0, stream>>>(w, mn, inv, nT);
    gemm_stats_k<<<BT_DIM / 32, 256, 0, stream>>>(x, pT, stats);
    output_k<<<BT_DIM / 4, 256, 0, stream>>>(x, nT, stats, out);
}